// Round 8
// baseline (1215.763 us; speedup 1.0000x reference)
//
#include <hip/hip_runtime.h>
#include <hip/hip_bf16.h>
#include <stdint.h>

#define D_IN    1408
#define D_HID   256
#define N_HEADS 32
#define BATCH   16384

#define BM 256            // rows per block
#define BN 256            // full head of hidden units
#define BK 64
#define KTILES (D_IN / BK)   // 22, exact (even -> static double-buffer parity)
#define NSEG 8               // segments per persistent block

typedef unsigned short u16;
typedef short short8 __attribute__((ext_vector_type(8)));
typedef float f32x4 __attribute__((ext_vector_type(4)));

// All inputs and the output are float32 (reference dtypes); compute is bf16
// MFMA (absmax 7.8e-3 vs threshold 2.4e-2, verified R1-R7).
__device__ __forceinline__ u16 f2b(float f) {
  __hip_bfloat16 h = __float2bfloat16(f);
  return *(u16*)&h;
}

// async global->LDS DMA, 16B/lane; LDS dest = wave-uniform base + lane*16.
__device__ __forceinline__ void gload_lds16(const void* g, void* l) {
  __builtin_amdgcn_global_load_lds(
      (const __attribute__((address_space(1))) uint32_t*)((const uint32_t*)g),
      (__attribute__((address_space(3))) uint32_t*)((uint32_t*)l),
      16, 0, 0);
}

// ---------------------------------------------------------------------------
// Kernel 0 (fused prep): convert X f32->bf16  AND  transpose W1 -> W1T bf16.
// ---------------------------------------------------------------------------
#define CONV_BLOCKS 22528   // (BATCH*D_IN/4)/256 float4s
__global__ void prep(const float4* __restrict__ X, ushort4* __restrict__ Xb,
                     const float* __restrict__ W1, u16* __restrict__ W1T) {
  const int bid = blockIdx.x;
  const int tid = threadIdx.x;
  if (bid < CONV_BLOCKS) {
    int i = bid * 256 + tid;
    float4 v = X[i];
    ushort4 o;
    o.x = f2b(v.x); o.y = f2b(v.y); o.z = f2b(v.z); o.w = f2b(v.w);
    Xb[i] = o;
    return;
  }
  // transpose part: b = f + 22*(o + 4*h)
  __shared__ u16 tile[64][68];
  const int b  = bid - CONV_BLOCKS;
  const int f0 = (b % 22) * 64;
  const int o0 = ((b / 22) & 3) * 64;
  const int h  = b / 88;
  const int tx = tid & 63;
  const int ty = tid >> 6;          // 0..3
  const size_t ib = (size_t)h * D_IN * D_HID;
  #pragma unroll
  for (int i = ty; i < 64; i += 4)
    tile[i][tx] = f2b(W1[ib + (size_t)(f0 + i) * D_HID + o0 + tx]);
  __syncthreads();
  const size_t ob = (size_t)h * D_HID * D_IN;
  #pragma unroll
  for (int pass = 0; pass < 4; ++pass) {
    int r = pass * 16 + ty * 4 + (tx >> 4);  // 0..63
    int c = (tx & 15) * 4;                   // 0..60
    ushort4 v;
    v.x = tile[c + 0][r]; v.y = tile[c + 1][r];
    v.z = tile[c + 2][r]; v.w = tile[c + 3][r];
    *(ushort4*)&W1T[ob + (size_t)(o0 + r) * D_IN + f0 + c] = v;
  }
}

// ---------------------------------------------------------------------------
// Kernel 1: PERSISTENT 256x256, A-in-LDS / B-IN-REGISTERS (from L2).
//
// R7 post-mortem: R4/R7 are LDS-BANDWIDTH-bound (64 b128 reads + DMA
// writes x 2 blocks ~= 100% of the 1565cy/tile budget); R3 same disease
// serialized. Root cause: B through LDS is pure waste -- every B element
// is read by exactly ONE wave (zero reuse amplification), yet B was 2/3
// of LDS write+read traffic and forced shared-buffer barriers. This rev:
//   - A (X): LDS as before (4-way cross-wave reuse), XOR-swizzled DMA,
//     2 buffers, 1-tile lead (free: tile ~3000cy >> 900cy HBM latency).
//   - B (W1T): per-lane global loads straight to DOUBLE-BUFFERED registers
//     (bA/bB, 64 VGPR -- affordable once B's LDS is gone). Address = the
//     fragment layout itself: lane (quad,l15) reads 16B at
//     col=nf*64+wn*16+l15, k=kt*64+ks*32+quad*8. 4 lanes/64B line, zero
//     overfetch, L2-resident slice (2.9MB/XCD), no barrier coverage needed.
//   - LDS traffic/tile drops 3x (128 reads+32KB DMA vs 192+64KB): LDS
//     ~1100-1500cy < MFMA 2480cy -> MFMA is the long pole for the first
//     time. vmcnt(0) + ONE barrier per tile; x2-unrolled K loop for static
//     register/buffer parity; B(t+1) at segment wrap = B(0) (same slice,
//     always in-bounds, no skip logic).
// Registers: acc 128 (AGPR) + a[8] 32 + bA/bB 64 + addr ~28 ~= 252 <= 256
// cap at 2 waves/SIMD (R3 measured 248 no-spill). Gate: WRITE_SIZE flat.
// Epilogue/params/persistence verbatim R2 (verified).
// ---------------------------------------------------------------------------
__global__ __launch_bounds__(512, 2) void mano_gemm(
    const u16* __restrict__ X,               // [16384][1408] bf16 (ws)
    const u16* __restrict__ W1T,             // [32][256][1408] bf16 (ws)
    const float* __restrict__ b1,            // [32][256] f32
    const float* __restrict__ W2,            // [32][256][3] f32
    const float* __restrict__ b2,            // [32][3] f32
    float* __restrict__ out)                 // [16384][96] f32 (d_out)
{
  __shared__ __align__(16) u16 As[2][BM * BK];   // 2 x 32 KB (A only!)
  __shared__ __align__(16) float scr[3072];      // 12 KB epilogue scratch
  __shared__ float b1L[256];                     // head-constant params
  __shared__ float w2L[768];
  __shared__ float b2L[3];

  const int tid  = threadIdx.x;     // 0..511
  const int lane = tid & 63;
  const int wid  = tid >> 6;        // 0..7
  const int quad = lane >> 4;
  const int l15  = lane & 15;
  const int wm   = wid >> 2;        // 0..1
  const int wn   = wid & 3;         // 0..3

  const int bid  = blockIdx.x;              // 0..255
  const int head = (bid & 7) * 4 + ((bid >> 3) & 3);   // constant per block
  const int u2   = bid >> 5;                           // 0..7

  const u16* Bu = W1T + (size_t)head * D_HID * D_IN;

  // ---- head-constant params -> LDS (once) ----
  if (tid < 256) b1L[tid] = b1[head * D_HID + tid];
  for (int i = tid; i < 768; i += 512) w2L[i] = W2[(size_t)head * D_HID * 3 + i];
  if (tid < 3)  b2L[tid] = b2[head * 3 + tid];

  // A staging: LDS chunk ci(16B) holds global [row=ci>>3][k8=(ci&7)^(row&7)]
  // (XOR pre-swizzled source, linear LDS; R1-R3 verified, 0 conflicts).
  // 2048 chunks / 512 threads = 4 per thread.
  int soff[4];
  #pragma unroll
  for (int c = 0; c < 4; ++c) {
    int ci  = c * 512 + tid;
    int row = ci >> 3;                 // 0..255
    int k8  = (ci & 7) ^ (row & 7);
    soff[c] = row * D_IN + k8 * 8;
  }

#define STG_A(BI, P) do { _Pragma("unroll")                                    \
    for (int c = 0; c < 4; ++c)                                                \
      gload_lds16((P) + soff[c], &As[BI][(c * 512 + wid * 64) * 8]); } while (0)

  // A frag read: row = mf*32 + wm*16 + l15 (interleaved, R2 style);
  // phys chunk = (ks*4+quad)^(row&7), row&7 == l15&7. Row stride 128 B.
  const int wm16l = wm * 16 + l15;
  const int rx  = l15 & 7;
  const int co0 = (quad ^ rx) * 16;
  const int co1 = ((4 + quad) ^ rx) * 16;

#define LDAF(BI, mf, CO)                                                       \
  (*(const short8*)((const char*)&As[BI][0] + ((mf) * 32 + wm16l) * 128 + (CO)))

  // B per-lane global offsets (u16 units): col = nf*64 + wn*16 + l15,
  // k-base = quad*8; full addr adds kt*BK + ks*32. 16B-aligned always.
  int bgo[4];
  #pragma unroll
  for (int nf = 0; nf < 4; ++nf)
    bgo[nf] = (nf * 64 + wn * 16 + l15) * D_IN + quad * 8;

  f32x4 acc[8][4];
  #pragma unroll
  for (int i = 0; i < 8; ++i)
    #pragma unroll
    for (int j = 0; j < 4; ++j)
      acc[i][j] = f32x4{0.f, 0.f, 0.f, 0.f};

  short8 a[8];            // A frags, one k-slice at a time
  short8 bA[4][2], bB[4][2];   // B double buffer (this tile / next tile)

  // One K64-tile: prefetch B(t+1)->BNXT (8 reg loads) + A(t+1) DMA, then
  // {read a ks0, 32 MFMA, read a ks1, 32 MFMA} with BCUR, vmcnt(0) (all
  // in-flight loads are a full tile old -> free), ONE barrier.
#define TILE(BI, APn, SKA, BCUR, BNXT, KTB) do {                               \
    _Pragma("unroll") for (int nf = 0; nf < 4; ++nf)                           \
      _Pragma("unroll") for (int ks = 0; ks < 2; ++ks)                         \
        BNXT[nf][ks] = *(const short8*)(Bu + bgo[nf] + (KTB) * BK + ks * 32);  \
    if (!(SKA)) STG_A((BI) ^ 1, APn);                                          \
    _Pragma("unroll") for (int mf = 0; mf < 8; ++mf) a[mf] = LDAF(BI, mf, co0);\
    __builtin_amdgcn_s_setprio(1);                                             \
    _Pragma("unroll") for (int mf = 0; mf < 8; ++mf)                           \
      _Pragma("unroll") for (int nf = 0; nf < 4; ++nf)                         \
        acc[mf][nf] = __builtin_amdgcn_mfma_f32_16x16x32_bf16(                 \
            a[mf], BCUR[nf][0], acc[mf][nf], 0, 0, 0);                         \
    __builtin_amdgcn_s_setprio(0);                                             \
    _Pragma("unroll") for (int mf = 0; mf < 8; ++mf) a[mf] = LDAF(BI, mf, co1);\
    __builtin_amdgcn_s_setprio(1);                                             \
    _Pragma("unroll") for (int mf = 0; mf < 8; ++mf)                           \
      _Pragma("unroll") for (int nf = 0; nf < 4; ++nf)                         \
        acc[mf][nf] = __builtin_amdgcn_mfma_f32_16x16x32_bf16(                 \
            a[mf], BCUR[nf][1], acc[mf][nf], 0, 0, 0);                         \
    __builtin_amdgcn_s_setprio(0);                                             \
    asm volatile("s_waitcnt vmcnt(0)" ::: "memory");                           \
    __builtin_amdgcn_s_barrier();                                              \
  } while (0)

  // ---- prologue: B(0) -> bA regs, A(0) -> buf0 ----
  {
    #pragma unroll
    for (int nf = 0; nf < 4; ++nf)
      #pragma unroll
      for (int ks = 0; ks < 2; ++ks)
        bA[nf][ks] = *(const short8*)(Bu + bgo[nf] + ks * 32);
    STG_A(0, X + (size_t)(u2 * BM) * D_IN);
    asm volatile("s_waitcnt lgkmcnt(0)" ::: "memory");  // param ds_writes done
    asm volatile("s_waitcnt vmcnt(0)" ::: "memory");
    __builtin_amdgcn_s_barrier();
  }

  #pragma unroll 1
  for (int g = 0; g < NSEG; ++g) {
    const u16* AuC = X + (size_t)((g * 8 + u2) * BM) * D_IN;
    const u16* AuN = AuC + (size_t)(8 * BM) * D_IN;   // next segment (g<7)
    const bool lastseg = (g == NSEG - 1);

    #pragma unroll 1
    for (int j = 0; j < KTILES / 2; ++j) {
      const int kt0 = 2 * j;
      // even tile: buf0, CUR=bA, stages A(kt0+1) (in-segment), B(kt0+1)
      TILE(0, AuC + (kt0 + 1) * BK, false, bA, bB, kt0 + 1);
      // odd tile: buf1, CUR=bB, stages A(kt0+2) (wraps at j=10), B((kt0+2)%22)
      const bool wrap = (j == KTILES / 2 - 1);
      const u16* Ap2 = wrap ? AuN : AuC + (kt0 + 2) * BK;
      const int  kB2 = wrap ? 0 : kt0 + 2;
      TILE(1, Ap2, lastseg && wrap, bB, bA, kB2);
    }

    // ---- fused epilogue (per segment): relu(acc+b1).W2, 4-wave combine ----
    // acc[mf][nf] elem (quad,r): row=mf*32+wm*16+quad*4+r, col=nf*64+wn16l
    {
      float b1v[4], w2v[4][3];
      #pragma unroll
      for (int nf = 0; nf < 4; ++nf) {
        int col = nf * 64 + wn * 16 + l15;
        b1v[nf] = b1L[col];
        #pragma unroll
        for (int p = 0; p < 3; ++p) w2v[nf][p] = w2L[col * 3 + p];
      }
      const int m0 = (g * 8 + u2) * BM;

      #pragma unroll
      for (int mf = 0; mf < 8; ++mf) {
        float ps[4][3];
        #pragma unroll
        for (int r = 0; r < 4; ++r)
          #pragma unroll
          for (int p = 0; p < 3; ++p) ps[r][p] = 0.f;

        #pragma unroll
        for (int nf = 0; nf < 4; ++nf)
          #pragma unroll
          for (int r = 0; r < 4; ++r) {
            float h = acc[mf][nf][r] + b1v[nf];
            h = h > 0.f ? h : 0.f;
            #pragma unroll
            for (int p = 0; p < 3; ++p)
              ps[r][p] = fmaf(h, w2v[nf][p], ps[r][p]);
          }

        // sum over the 16 column-lanes (xor on low 4 lane bits stays in-quad)
        #pragma unroll
        for (int mask = 1; mask < 16; mask <<= 1)
          #pragma unroll
          for (int r = 0; r < 4; ++r)
            #pragma unroll
            for (int p = 0; p < 3; ++p)
              ps[r][p] += __shfl_xor(ps[r][p], mask, 64);

        if (l15 == 0) {
          int row = mf * 32 + wm * 16 + quad * 4;          // +r below
          #pragma unroll
          for (int r = 0; r < 4; ++r)
            #pragma unroll
            for (int p = 0; p < 3; ++p)
              scr[((row + r) * 3 + p) * 4 + wn] = ps[r][p];
        }
      }
      // raw barrier (NOT __syncthreads: next-seg A(0) DMA already drained at
      // the last tile's vmcnt(0); only ds ordering needed here)
      asm volatile("s_waitcnt lgkmcnt(0)" ::: "memory");
      __builtin_amdgcn_s_barrier();

      for (int i = tid; i < BM * 3; i += 512) {
        int row = i / 3, p = i - row * 3;
        float v = scr[i * 4 + 0] + scr[i * 4 + 1] + scr[i * 4 + 2]
                + scr[i * 4 + 3] + b2L[p];
        out[(size_t)(m0 + row) * (N_HEADS * 3) + head * 3 + p] = v;
      }

      #pragma unroll
      for (int i = 0; i < 8; ++i)
        #pragma unroll
        for (int jj = 0; jj < 4; ++jj)
          acc[i][jj] = f32x4{0.f, 0.f, 0.f, 0.f};
      // scr not rewritten until the next epilogue, 22 tile-barriers away;
      // next TILE touches As/bA/bB (disjoint from scr) -> no extra barrier.
    }
  }

#undef STG_A
#undef LDAF
#undef TILE
}

extern "C" void kernel_launch(void* const* d_in, const int* in_sizes, int n_in,
                              void* d_out, int out_size, void* d_ws, size_t ws_size,
                              hipStream_t stream) {
  const float* X  = (const float*)d_in[0];
  const float* W1 = (const float*)d_in[1];
  const float* b1 = (const float*)d_in[2];
  const float* W2 = (const float*)d_in[3];
  const float* b2 = (const float*)d_in[4];

  // ws: Xb 46,137,344 | W1T 23,068,672  = 69,206,016 B (proven fits)
  u16* Xb  = (u16*)d_ws;
  u16* W1T = (u16*)((char*)d_ws + (size_t)BATCH * D_IN * 2);

  prep<<<CONV_BLOCKS + (D_IN / 64) * (D_HID / 64) * N_HEADS, 256, 0, stream>>>(
      (const float4*)X, (ushort4*)Xb, W1, W1T);

  mano_gemm<<<dim3(256), 512, 0, stream>>>(
      Xb, W1T, b1, W2, b2, (float*)d_out);
}

// Round 9
// 1069.463 us; speedup vs baseline: 1.1368x; 1.1368x over previous
//
#include <hip/hip_runtime.h>
#include <hip/hip_bf16.h>
#include <stdint.h>

#define D_IN    1408
#define D_HID   256
#define N_HEADS 32
#define BATCH   16384

#define BM 128            // rows per block
#define BN 256            // full head of hidden units
#define BK 64
#define KTILES (D_IN / BK)   // 22, exact (even -> static double-buffer parity)
#define NSEG 16              // segments per persistent block

typedef unsigned short u16;
typedef short short8 __attribute__((ext_vector_type(8)));
typedef float f32x4 __attribute__((ext_vector_type(4)));

// All inputs and the output are float32 (reference dtypes); compute is bf16
// MFMA (absmax 7.8e-3 vs threshold 2.4e-2, verified R1-R8).
__device__ __forceinline__ u16 f2b(float f) {
  __hip_bfloat16 h = __float2bfloat16(f);
  return *(u16*)&h;
}

// async global->LDS DMA, 16B/lane; LDS dest = wave-uniform base + lane*16.
__device__ __forceinline__ void gload_lds16(const void* g, void* l) {
  __builtin_amdgcn_global_load_lds(
      (const __attribute__((address_space(1))) uint32_t*)((const uint32_t*)g),
      (__attribute__((address_space(3))) uint32_t*)((uint32_t*)l),
      16, 0, 0);
}

// ---------------------------------------------------------------------------
// Kernel 0 (fused prep): convert X f32->bf16  AND  transpose W1 -> W1T bf16.
// ---------------------------------------------------------------------------
#define CONV_BLOCKS 22528   // (BATCH*D_IN/4)/256 float4s
__global__ void prep(const float4* __restrict__ X, ushort4* __restrict__ Xb,
                     const float* __restrict__ W1, u16* __restrict__ W1T) {
  const int bid = blockIdx.x;
  const int tid = threadIdx.x;
  if (bid < CONV_BLOCKS) {
    int i = bid * 256 + tid;
    float4 v = X[i];
    ushort4 o;
    o.x = f2b(v.x); o.y = f2b(v.y); o.z = f2b(v.z); o.w = f2b(v.w);
    Xb[i] = o;
    return;
  }
  // transpose part: b = f + 22*(o + 4*h)
  __shared__ u16 tile[64][68];
  const int b  = bid - CONV_BLOCKS;
  const int f0 = (b % 22) * 64;
  const int o0 = ((b / 22) & 3) * 64;
  const int h  = b / 88;
  const int tx = tid & 63;
  const int ty = tid >> 6;          // 0..3
  const size_t ib = (size_t)h * D_IN * D_HID;
  #pragma unroll
  for (int i = ty; i < 64; i += 4)
    tile[i][tx] = f2b(W1[ib + (size_t)(f0 + i) * D_HID + o0 + tx]);
  __syncthreads();
  const size_t ob = (size_t)h * D_HID * D_IN;
  #pragma unroll
  for (int pass = 0; pass < 4; ++pass) {
    int r = pass * 16 + ty * 4 + (tx >> 4);  // 0..63
    int c = (tx & 15) * 4;                   // 0..60
    ushort4 v;
    v.x = tile[c + 0][r]; v.y = tile[c + 1][r];
    v.z = tile[c + 2][r]; v.w = tile[c + 3][r];
    *(ushort4*)&W1T[ob + (size_t)(o0 + r) * D_IN + f0 + c] = v;
  }
}

// ---------------------------------------------------------------------------
// Kernel 1: PERSISTENT 128x256, A-in-LDS / B-in-registers, REGISTER-SAFE.
//
// R8 post-mortem: B-in-regs at BM=256 needed ~259 unified regs > 256 cap ->
// cascade spill (WRITE_SIZE 8MB -> 1.29GB). The mechanism was never tested.
// This rev shrinks the accumulator so the math clears with margin:
//   - block 128x256, 8 waves, wave = 64x64: acc 16 f32x4 = 64 AGPR;
//     B dbuf 64 + a[4] 16 + addr ~30 -> unified ~195 <= 256 (60 spare).
//   - LDS holds A ONLY (2 x 16 KB). Per-tile LDS reads = 64 KB (~770cy),
//     first time BELOW the MFMA floor (128*256*64*2 / 3376 FLOP/cy =
//     1242cy). B's LDS write+2x-read share is deleted outright.
//   - B (W1T, head-constant, L2-resident) streams straight to double-
//     buffered registers: 8 global_load_dwordx4/wave/tile at the fragment
//     layout (col=wn*64+nf*16+l15, k=quad*8), full-tile prefetch lead
//     (~1400cy >> 900cy HBM / 200cy L2), no barrier coverage (private).
//   - one vmcnt(0) + one barrier per tile (lead = full tile -> free, per
//     R7 measurement). sched_barrier(0) pins prefetch issues early.
//   - persistent head-constant blocks, 16 segments x 22 tiles; B wraps to
//     k=0 at segment end (same slice, always loadable).
// Gates: WRITE_SIZE ~8 MB flat, VGPR ~110-140. Swizzle verbatim R1-R7.
// ---------------------------------------------------------------------------
__global__ __launch_bounds__(512, 2) void mano_gemm(
    const u16* __restrict__ X,               // [16384][1408] bf16 (ws)
    const u16* __restrict__ W1T,             // [32][256][1408] bf16 (ws)
    const float* __restrict__ b1,            // [32][256] f32
    const float* __restrict__ W2,            // [32][256][3] f32
    const float* __restrict__ b2,            // [32][3] f32
    float* __restrict__ out)                 // [16384][96] f32 (d_out)
{
  __shared__ __align__(16) u16 As[2][BM * BK];   // 2 x 16 KB (A only)
  __shared__ __align__(16) float scr[1536];      // 6 KB epilogue scratch
  __shared__ float b1L[256];                     // head-constant params
  __shared__ float w2L[768];
  __shared__ float b2L[3];

  const int tid  = threadIdx.x;     // 0..511
  const int lane = tid & 63;
  const int wid  = tid >> 6;        // 0..7
  const int quad = lane >> 4;
  const int l15  = lane & 15;
  const int wm   = wid >> 2;        // 0..1 (64-row half)
  const int wn   = wid & 3;         // 0..3 (64-col band)

  const int bid  = blockIdx.x;              // 0..255
  const int head = (bid & 7) * 4 + ((bid >> 3) & 3);   // constant per block
  const int u    = bid >> 5;                           // 0..7

  const u16* Bu = W1T + (size_t)head * D_HID * D_IN;

  // ---- head-constant params -> LDS (once) ----
  if (tid < 256) b1L[tid] = b1[head * D_HID + tid];
  for (int i = tid; i < 768; i += 512) w2L[i] = W2[(size_t)head * D_HID * 3 + i];
  if (tid < 3)  b2L[tid] = b2[head * 3 + tid];

  // A staging: LDS chunk ci(16B) holds global [row=ci>>3][k8=(ci&7)^(row&7)]
  // (XOR pre-swizzled source, linear LDS; R1-R7 verified, 0 conflicts).
  // 1024 chunks / 512 threads = 2 per thread.
  int soff[2];
  #pragma unroll
  for (int c = 0; c < 2; ++c) {
    int ci  = c * 512 + tid;
    int row = ci >> 3;                 // 0..127
    int k8  = (ci & 7) ^ (row & 7);
    soff[c] = row * D_IN + k8 * 8;
  }

#define STG_A(BI, P) do { _Pragma("unroll")                                    \
    for (int c = 0; c < 2; ++c)                                                \
      gload_lds16((P) + soff[c], &As[BI][(c * 512 + wid * 64) * 8]); } while (0)

  // A frag read: row = wm*64 + mf*16 + l15; phys chunk = (ks*4+quad)^(row&7),
  // row&7 == l15&7. Row stride 128 B; byte addr = row*128 + chunk*16.
  const int rx  = l15 & 7;
  const int co0 = (quad ^ rx) * 16;
  const int co1 = ((4 + quad) ^ rx) * 16;
  const int abase = (wm * 64 + l15) * 128;   // + mf*2048

#define LDAF(BI, mf, CO)                                                       \
  (*(const short8*)((const char*)&As[BI][0] + abase + (mf) * 2048 + (CO)))

  // B per-lane global offsets (u16 units): col = wn*64 + nf*16 + l15,
  // k-base = quad*8; full addr adds kt*BK + ks*32. 16B-aligned always.
  int bgo[4];
  #pragma unroll
  for (int nf = 0; nf < 4; ++nf)
    bgo[nf] = (wn * 64 + nf * 16 + l15) * D_IN + quad * 8;

  f32x4 acc[4][4];
  #pragma unroll
  for (int i = 0; i < 4; ++i)
    #pragma unroll
    for (int j = 0; j < 4; ++j)
      acc[i][j] = f32x4{0.f, 0.f, 0.f, 0.f};

  short8 a[4];                 // A frags, one k-slice at a time
  short8 bA[4][2], bB[4][2];   // B double buffer (this tile / next tile)

  // One K64-tile: issue B(t+1)->BNXT (8 reg loads) + A(t+1) DMA, pin them
  // early (sched_barrier), then {read a ks0, 16 MFMA, read a ks1, 16 MFMA}
  // with BCUR; vmcnt(0) (all in-flight loads a full tile old -> free); ONE
  // barrier.
#define TILE(BI, APn, SKA, BCUR, BNXT, KTB) do {                               \
    _Pragma("unroll") for (int nf = 0; nf < 4; ++nf)                           \
      _Pragma("unroll") for (int ks = 0; ks < 2; ++ks)                         \
        BNXT[nf][ks] = *(const short8*)(Bu + bgo[nf] + (KTB) * BK + ks * 32);  \
    if (!(SKA)) STG_A((BI) ^ 1, APn);                                          \
    __builtin_amdgcn_sched_barrier(0);                                         \
    _Pragma("unroll") for (int mf = 0; mf < 4; ++mf) a[mf] = LDAF(BI, mf, co0);\
    __builtin_amdgcn_s_setprio(1);                                             \
    _Pragma("unroll") for (int mf = 0; mf < 4; ++mf)                           \
      _Pragma("unroll") for (int nf = 0; nf < 4; ++nf)                         \
        acc[mf][nf] = __builtin_amdgcn_mfma_f32_16x16x32_bf16(                 \
            a[mf], BCUR[nf][0], acc[mf][nf], 0, 0, 0);                         \
    __builtin_amdgcn_s_setprio(0);                                             \
    _Pragma("unroll") for (int mf = 0; mf < 4; ++mf) a[mf] = LDAF(BI, mf, co1);\
    __builtin_amdgcn_s_setprio(1);                                             \
    _Pragma("unroll") for (int mf = 0; mf < 4; ++mf)                           \
      _Pragma("unroll") for (int nf = 0; nf < 4; ++nf)                         \
        acc[mf][nf] = __builtin_amdgcn_mfma_f32_16x16x32_bf16(                 \
            a[mf], BCUR[nf][1], acc[mf][nf], 0, 0, 0);                         \
    __builtin_amdgcn_s_setprio(0);                                             \
    asm volatile("s_waitcnt vmcnt(0)" ::: "memory");                           \
    __builtin_amdgcn_s_barrier();                                              \
  } while (0)

  // ---- prologue: B(0) -> bA regs, A(0) -> buf0 ----
  {
    #pragma unroll
    for (int nf = 0; nf < 4; ++nf)
      #pragma unroll
      for (int ks = 0; ks < 2; ++ks)
        bA[nf][ks] = *(const short8*)(Bu + bgo[nf] + ks * 32);
    STG_A(0, X + (size_t)(u * BM) * D_IN);
    asm volatile("s_waitcnt lgkmcnt(0)" ::: "memory");  // param ds_writes done
    asm volatile("s_waitcnt vmcnt(0)" ::: "memory");
    __builtin_amdgcn_s_barrier();
  }

  #pragma unroll 1
  for (int g = 0; g < NSEG; ++g) {
    const u16* AuC = X + (size_t)((g * 8 + u) * BM) * D_IN;
    const u16* AuN = AuC + (size_t)(8 * BM) * D_IN;   // next segment (g<15)
    const bool lastseg = (g == NSEG - 1);

    #pragma unroll 1
    for (int j = 0; j < KTILES / 2; ++j) {
      const int kt0 = 2 * j;
      // even tile: buf0, CUR=bA, stages A(kt0+1) (in-segment), B(kt0+1)->bB
      TILE(0, AuC + (kt0 + 1) * BK, false, bA, bB, kt0 + 1);
      // odd tile: buf1, CUR=bB, stages A(kt0+2) (wraps at j=10), B->bA
      const bool wrap = (j == KTILES / 2 - 1);
      const u16* Ap2 = wrap ? AuN : AuC + (kt0 + 2) * BK;
      const int  kB2 = wrap ? 0 : kt0 + 2;
      TILE(1, Ap2, lastseg && wrap, bB, bA, kB2);
    }

    // ---- fused epilogue (per segment): relu(acc+b1).W2, 4-wave combine ----
    // acc[mf][nf] elem (quad,r): row = wm*64+mf*16+quad*4+r (0..127),
    //                            col = wn*64+nf*16+l15
    {
      float b1v[4], w2v[4][3];
      #pragma unroll
      for (int nf = 0; nf < 4; ++nf) {
        int col = wn * 64 + nf * 16 + l15;
        b1v[nf] = b1L[col];
        #pragma unroll
        for (int p = 0; p < 3; ++p) w2v[nf][p] = w2L[col * 3 + p];
      }
      const int m0 = (g * 8 + u) * BM;

      #pragma unroll
      for (int mf = 0; mf < 4; ++mf) {
        float ps[4][3];
        #pragma unroll
        for (int r = 0; r < 4; ++r)
          #pragma unroll
          for (int p = 0; p < 3; ++p) ps[r][p] = 0.f;

        #pragma unroll
        for (int nf = 0; nf < 4; ++nf)
          #pragma unroll
          for (int r = 0; r < 4; ++r) {
            float h = acc[mf][nf][r] + b1v[nf];
            h = h > 0.f ? h : 0.f;
            #pragma unroll
            for (int p = 0; p < 3; ++p)
              ps[r][p] = fmaf(h, w2v[nf][p], ps[r][p]);
          }

        // sum over the 16 column-lanes (xor on low 4 lane bits stays in-quad)
        #pragma unroll
        for (int mask = 1; mask < 16; mask <<= 1)
          #pragma unroll
          for (int r = 0; r < 4; ++r)
            #pragma unroll
            for (int p = 0; p < 3; ++p)
              ps[r][p] += __shfl_xor(ps[r][p], mask, 64);

        if (l15 == 0) {
          int row = wm * 64 + mf * 16 + quad * 4;          // +r below
          #pragma unroll
          for (int r = 0; r < 4; ++r)
            #pragma unroll
            for (int p = 0; p < 3; ++p)
              scr[((row + r) * 3 + p) * 4 + wn] = ps[r][p];
        }
      }
      // raw barrier (NOT __syncthreads: next-seg A(0) DMA already drained at
      // the last tile's vmcnt(0); only ds ordering needed here)
      asm volatile("s_waitcnt lgkmcnt(0)" ::: "memory");
      __builtin_amdgcn_s_barrier();

      if (tid < BM * 3) {
        int row = tid / 3, p = tid - row * 3;
        float v = scr[tid * 4 + 0] + scr[tid * 4 + 1] + scr[tid * 4 + 2]
                + scr[tid * 4 + 3] + b2L[p];
        out[(size_t)(m0 + row) * (N_HEADS * 3) + head * 3 + p] = v;
      }

      #pragma unroll
      for (int i = 0; i < 4; ++i)
        #pragma unroll
        for (int jj = 0; jj < 4; ++jj)
          acc[i][jj] = f32x4{0.f, 0.f, 0.f, 0.f};
      // scr not rewritten until the next epilogue, 22 tile-barriers away;
      // next TILE touches As/bA/bB (disjoint from scr) -> no extra barrier.
    }
  }

#undef STG_A
#undef LDAF
#undef TILE
}

extern "C" void kernel_launch(void* const* d_in, const int* in_sizes, int n_in,
                              void* d_out, int out_size, void* d_ws, size_t ws_size,
                              hipStream_t stream) {
  const float* X  = (const float*)d_in[0];
  const float* W1 = (const float*)d_in[1];
  const float* b1 = (const float*)d_in[2];
  const float* W2 = (const float*)d_in[3];
  const float* b2 = (const float*)d_in[4];

  // ws: Xb 46,137,344 | W1T 23,068,672  = 69,206,016 B (proven fits)
  u16* Xb  = (u16*)d_ws;
  u16* W1T = (u16*)((char*)d_ws + (size_t)BATCH * D_IN * 2);

  prep<<<CONV_BLOCKS + (D_IN / 64) * (D_HID / 64) * N_HEADS, 256, 0, stream>>>(
      (const float4*)X, (ushort4*)Xb, W1, W1T);

  mano_gemm<<<dim3(256), 512, 0, stream>>>(
      Xb, W1T, b1, W2, b2, (float*)d_out);
}

// Round 10
// 791.740 us; speedup vs baseline: 1.5356x; 1.3508x over previous
//
#include <hip/hip_runtime.h>
#include <hip/hip_bf16.h>
#include <stdint.h>

#define D_IN    1408
#define D_HID   256
#define N_HEADS 32
#define BATCH   16384

#define BM 128            // rows per block
#define BN 256            // full head of hidden units
#define BK 64
#define KTILES (D_IN / BK)   // 22, exact (even -> static A-buffer parity)
#define NSEG 8               // segments per persistent block

typedef unsigned short u16;
typedef short short8 __attribute__((ext_vector_type(8)));
typedef float f32x4 __attribute__((ext_vector_type(4)));

// All inputs and the output are float32 (reference dtypes); compute is bf16
// MFMA (absmax 7.8e-3 vs threshold 2.4e-2, verified R1-R9).
__device__ __forceinline__ u16 f2b(float f) {
  __hip_bfloat16 h = __float2bfloat16(f);
  return *(u16*)&h;
}

// async global->LDS DMA, 16B/lane; LDS dest = wave-uniform base + lane*16.
__device__ __forceinline__ void gload_lds16(const void* g, void* l) {
  __builtin_amdgcn_global_load_lds(
      (const __attribute__((address_space(1))) uint32_t*)((const uint32_t*)g),
      (__attribute__((address_space(3))) uint32_t*)((uint32_t*)l),
      16, 0, 0);
}

// ---------------------------------------------------------------------------
// Kernel 0 (fused prep): convert X f32->bf16  AND  transpose W1 -> W1T bf16.
// ---------------------------------------------------------------------------
#define CONV_BLOCKS 22528   // (BATCH*D_IN/4)/256 float4s
__global__ void prep(const float4* __restrict__ X, ushort4* __restrict__ Xb,
                     const float* __restrict__ W1, u16* __restrict__ W1T) {
  const int bid = blockIdx.x;
  const int tid = threadIdx.x;
  if (bid < CONV_BLOCKS) {
    int i = bid * 256 + tid;
    float4 v = X[i];
    ushort4 o;
    o.x = f2b(v.x); o.y = f2b(v.y); o.z = f2b(v.z); o.w = f2b(v.w);
    Xb[i] = o;
    return;
  }
  // transpose part: b = f + 22*(o + 4*h)
  __shared__ u16 tile[64][68];
  const int b  = bid - CONV_BLOCKS;
  const int f0 = (b % 22) * 64;
  const int o0 = ((b / 22) & 3) * 64;
  const int h  = b / 88;
  const int tx = tid & 63;
  const int ty = tid >> 6;          // 0..3
  const size_t ib = (size_t)h * D_IN * D_HID;
  #pragma unroll
  for (int i = ty; i < 64; i += 4)
    tile[i][tx] = f2b(W1[ib + (size_t)(f0 + i) * D_HID + o0 + tx]);
  __syncthreads();
  const size_t ob = (size_t)h * D_HID * D_IN;
  #pragma unroll
  for (int pass = 0; pass < 4; ++pass) {
    int r = pass * 16 + ty * 4 + (tx >> 4);  // 0..63
    int c = (tx & 15) * 4;                   // 0..60
    ushort4 v;
    v.x = tile[c + 0][r]; v.y = tile[c + 1][r];
    v.z = tile[c + 2][r]; v.w = tile[c + 3][r];
    *(ushort4*)&W1T[ob + (size_t)(o0 + r) * D_IN + f0 + c] = v;
  }
}

// ---------------------------------------------------------------------------
// Kernel 1: PERSISTENT 128x256 / 4 waves (1x4) / 2 blocks/CU, BK=64.
//
// R9 post-mortem: direct-to-reg B loads are GATHERS (lane->col strided
// 2816B) -> VMEM address-processing bound (16% MfmaUtil). B must transit
// LDS. Ledger correction: R7 was per-tile-OVERHEAD-bound (BK=32), not
// LDS-bound -> cross-block TLP at a viable tile size is untested. This rev:
//   - 4 waves (wn=0..3), wave = 128x64 (the proven 248-reg budget: acc 128
//     AGPR + frags 64 + addr ~30). With 1 wm band, B-reuse = 1 -> B's LDS
//     region is WAVE-PRIVATE: single-buffered 8KB/wave, no barrier, no
//     dbuf. Reads(t) retire (lgkmcnt(0) + sched_barrier(0), rule-18 fence)
//     BEFORE B-DMA(t+1) issues -> no race. A (4-way reuse): block DMA,
//     2x16KB dbuf, ONE vmcnt(0)+barrier per tile.
//   - LDS/block = A 32K + B 32K + scr 6K + params 4K ~ 76KB -> TWO
//     independent blocks/CU (each SIMD: 1 wave from each block). Per CU
//     per 2 tiles: LDS ~2570cy ~= MFMA 2480cy -> anti-phase blocks overlap
//     the pipes (m114), no block-wide lockstep possible across blocks.
//   - BK=64 amortizes the ~650cy/tile sync overhead that killed R4/R7.
//   - per-tile ops/wave: 4 A-DMA, 16+8 ds_read, 8 B-DMA, 64 MFMA, 1 bar.
// Persistent 512 blocks, head-constant (b1/W2 LDS; W1T slice L2-resident),
// 8 segments x 22 tiles; B wraps k->0 at seg end. Swizzles verbatim R1-R9
// (0 conflicts measured).
// ---------------------------------------------------------------------------
__global__ __launch_bounds__(256, 2) void mano_gemm(
    const u16* __restrict__ X,               // [16384][1408] bf16 (ws)
    const u16* __restrict__ W1T,             // [32][256][1408] bf16 (ws)
    const float* __restrict__ b1,            // [32][256] f32
    const float* __restrict__ W2,            // [32][256][3] f32
    const float* __restrict__ b2,            // [32][3] f32
    float* __restrict__ out)                 // [16384][96] f32 (d_out)
{
  __shared__ __align__(16) u16 Asd[2][BM * BK];   // 2 x 16 KB (shared, dbuf)
  __shared__ __align__(16) u16 Bsd[4][64 * BK];   // 4 x 8 KB (wave-private)
  __shared__ __align__(16) float scr[1536];       // 6 KB epilogue scratch
  __shared__ float b1L[256];                      // head-constant params
  __shared__ float w2L[768];
  __shared__ float b2L[3];

  const int tid  = threadIdx.x;     // 0..255
  const int lane = tid & 63;
  const int wid  = tid >> 6;        // 0..3 == wn (64-col band)
  const int quad = lane >> 4;
  const int l15  = lane & 15;

  const int bid  = blockIdx.x;              // 0..511
  const int head = (bid & 7) * 4 + ((bid >> 3) & 3);   // constant per block
  const int u    = bid >> 5;                           // 0..15

  const u16* Bu = W1T + (size_t)head * D_HID * D_IN;

  // ---- head-constant params -> LDS (once) ----
  b1L[tid] = b1[head * D_HID + tid];
  #pragma unroll
  for (int i = tid; i < 768; i += 256) w2L[i] = W2[(size_t)head * D_HID * 3 + i];
  if (tid < 3) b2L[tid] = b2[head * 3 + tid];

  // A staging (block-wide): LDS chunk ci(16B) holds global
  // [row=ci>>3][k8=(ci&7)^(row&7)]. 1024 chunks / 256 threads = 4.
  int soff[4];
  #pragma unroll
  for (int c = 0; c < 4; ++c) {
    int ci  = c * 256 + tid;
    int row = ci >> 3;                 // 0..127
    int k8  = (ci & 7) ^ (row & 7);
    soff[c] = row * D_IN + k8 * 8;
  }
  // B staging (wave-private): chunk cj(16B) of wave wid's region holds
  // global [col=wn*64 + (cj>>3)][k8=(cj&7)^((cj>>3)&7)]. 512 chunks/64 lanes.
  int bsoff[8];
  #pragma unroll
  for (int c = 0; c < 8; ++c) {
    int cj   = c * 64 + lane;
    int brow = cj >> 3;                // 0..63
    int k8   = (cj & 7) ^ (brow & 7);
    bsoff[c] = (wid * 64 + brow) * D_IN + k8 * 8;
  }

  // frag reads: A row = mf*16+l15 (0..127); B row = nf*16+l15 (band-local);
  // phys chunk = (ks*4+quad)^(row&7), row&7 == l15&7; row stride 128 B.
  const int rx  = l15 & 7;
  const int co0 = (quad ^ rx) * 16;
  const int co1 = ((4 + quad) ^ rx) * 16;
  const int aro = l15 * 128;   // + mf*2048
  const int bro = l15 * 128;   // + nf*2048, within Bsd[wid]

#define LDAF(BI, mf, CO)                                                       \
  (*(const short8*)((const char*)&Asd[BI][0] + aro + (mf) * 2048 + (CO)))
#define LDBF(nf, CO)                                                           \
  (*(const short8*)((const char*)&Bsd[wid][0] + bro + (nf) * 2048 + (CO)))

  f32x4 acc[8][4];
  #pragma unroll
  for (int i = 0; i < 8; ++i)
    #pragma unroll
    for (int j = 0; j < 4; ++j)
      acc[i][j] = f32x4{0.f, 0.f, 0.f, 0.f};

  short8 a[8], b[4][2];

  // One K64-tile:
  //  1) A(t+1) DMA -> other buf (4 issues)
  //  2) read ALL B frags (8) + A ks0 frags (8)
  //  3) lgkmcnt(0) + sched_barrier  -> B reads retired (single-buffer safe)
  //  4) B(t+1) DMA into the same private region (8 issues)
  //  5) 32 MFMA (ks0)  |  6) read A ks1 (8)  |  7) 32 MFMA (ks1)
  //  8) vmcnt(0) (this tile's DMAs, ~1.5-2.5Ktile-cy old) + ONE barrier
#define TILE(BI, APn, BKT, SK) do {                                            \
    if (!(SK)) { _Pragma("unroll")                                             \
      for (int c = 0; c < 4; ++c)                                              \
        gload_lds16((APn) + soff[c], &Asd[(BI) ^ 1][(c * 256 + wid * 64) * 8]);\
    }                                                                          \
    _Pragma("unroll") for (int nf = 0; nf < 4; ++nf) {                         \
      b[nf][0] = LDBF(nf, co0); b[nf][1] = LDBF(nf, co1); }                    \
    _Pragma("unroll") for (int mf = 0; mf < 8; ++mf) a[mf] = LDAF(BI, mf, co0);\
    asm volatile("s_waitcnt lgkmcnt(0)" ::: "memory");                         \
    __builtin_amdgcn_sched_barrier(0);                                         \
    if (!(SK)) { _Pragma("unroll")                                             \
      for (int c = 0; c < 8; ++c)                                              \
        gload_lds16(Bu + bsoff[c] + (BKT) * BK, &Bsd[wid][c * 512]);           \
    }                                                                          \
    __builtin_amdgcn_s_setprio(1);                                             \
    _Pragma("unroll") for (int mf = 0; mf < 8; ++mf)                           \
      _Pragma("unroll") for (int nf = 0; nf < 4; ++nf)                         \
        acc[mf][nf] = __builtin_amdgcn_mfma_f32_16x16x32_bf16(                 \
            a[mf], b[nf][0], acc[mf][nf], 0, 0, 0);                            \
    __builtin_amdgcn_s_setprio(0);                                             \
    _Pragma("unroll") for (int mf = 0; mf < 8; ++mf) a[mf] = LDAF(BI, mf, co1);\
    __builtin_amdgcn_s_setprio(1);                                             \
    _Pragma("unroll") for (int mf = 0; mf < 8; ++mf)                           \
      _Pragma("unroll") for (int nf = 0; nf < 4; ++nf)                         \
        acc[mf][nf] = __builtin_amdgcn_mfma_f32_16x16x32_bf16(                 \
            a[mf], b[nf][1], acc[mf][nf], 0, 0, 0);                            \
    __builtin_amdgcn_s_setprio(0);                                             \
    asm volatile("s_waitcnt vmcnt(0)" ::: "memory");                           \
    __builtin_amdgcn_s_barrier();                                              \
  } while (0)

  // ---- prologue: A(0) -> buf0, B(0) -> private regions ----
  {
    const u16* A0 = X + (size_t)(u * BM) * D_IN;
    #pragma unroll
    for (int c = 0; c < 4; ++c)
      gload_lds16(A0 + soff[c], &Asd[0][(c * 256 + wid * 64) * 8]);
    #pragma unroll
    for (int c = 0; c < 8; ++c)
      gload_lds16(Bu + bsoff[c], &Bsd[wid][c * 512]);
    asm volatile("s_waitcnt lgkmcnt(0)" ::: "memory");  // param ds_writes done
    asm volatile("s_waitcnt vmcnt(0)" ::: "memory");
    __builtin_amdgcn_s_barrier();
  }

  #pragma unroll 1
  for (int g = 0; g < NSEG; ++g) {
    const u16* AuC = X + (size_t)((g * 16 + u) * BM) * D_IN;
    const u16* AuN = AuC + (size_t)(16 * BM) * D_IN;   // next segment (g<7)
    const bool lastseg = (g == NSEG - 1);

    #pragma unroll 1
    for (int j = 0; j < KTILES / 2; ++j) {
      const int kt0 = 2 * j;
      // even tile: A buf0, stages t+1 = kt0+1 (always in-segment)
      TILE(0, AuC + (kt0 + 1) * BK, kt0 + 1, false);
      // odd tile: A buf1, stages t+1 = kt0+2 (wraps to next seg at j=10)
      const bool wrap = (j == KTILES / 2 - 1);
      const u16* Ap2 = wrap ? AuN : AuC + (kt0 + 2) * BK;
      const int  kB2 = wrap ? 0 : kt0 + 2;
      TILE(1, Ap2, kB2, lastseg && wrap);
    }

    // ---- fused epilogue (per segment): relu(acc+b1).W2, 4-wave combine ----
    // acc[mf][nf] elem (quad,r): row = mf*16+quad*4+r (0..127),
    //                            col = wid*64+nf*16+l15
    {
      float b1v[4], w2v[4][3];
      #pragma unroll
      for (int nf = 0; nf < 4; ++nf) {
        int col = wid * 64 + nf * 16 + l15;
        b1v[nf] = b1L[col];
        #pragma unroll
        for (int p = 0; p < 3; ++p) w2v[nf][p] = w2L[col * 3 + p];
      }
      const int m0 = (g * 16 + u) * BM;

      #pragma unroll
      for (int mf = 0; mf < 8; ++mf) {
        float ps[4][3];
        #pragma unroll
        for (int r = 0; r < 4; ++r)
          #pragma unroll
          for (int p = 0; p < 3; ++p) ps[r][p] = 0.f;

        #pragma unroll
        for (int nf = 0; nf < 4; ++nf)
          #pragma unroll
          for (int r = 0; r < 4; ++r) {
            float h = acc[mf][nf][r] + b1v[nf];
            h = h > 0.f ? h : 0.f;
            #pragma unroll
            for (int p = 0; p < 3; ++p)
              ps[r][p] = fmaf(h, w2v[nf][p], ps[r][p]);
          }

        // sum over the 16 column-lanes (xor on low 4 lane bits stays in-quad)
        #pragma unroll
        for (int mask = 1; mask < 16; mask <<= 1)
          #pragma unroll
          for (int r = 0; r < 4; ++r)
            #pragma unroll
            for (int p = 0; p < 3; ++p)
              ps[r][p] += __shfl_xor(ps[r][p], mask, 64);

        if (l15 == 0) {
          int row = mf * 16 + quad * 4;          // +r below
          #pragma unroll
          for (int r = 0; r < 4; ++r)
            #pragma unroll
            for (int p = 0; p < 3; ++p)
              scr[((row + r) * 3 + p) * 4 + wid] = ps[r][p];
        }
      }
      // raw barrier (NOT __syncthreads: next-seg DMAs were drained at the
      // last tile's vmcnt(0); only ds ordering needed here)
      asm volatile("s_waitcnt lgkmcnt(0)" ::: "memory");
      __builtin_amdgcn_s_barrier();

      #pragma unroll
      for (int i = tid; i < BM * 3; i += 256) {
        int row = i / 3, p = i - row * 3;
        float v = scr[i * 4 + 0] + scr[i * 4 + 1] + scr[i * 4 + 2]
                + scr[i * 4 + 3] + b2L[p];
        out[(size_t)(m0 + row) * (N_HEADS * 3) + head * 3 + p] = v;
      }

      #pragma unroll
      for (int i = 0; i < 8; ++i)
        #pragma unroll
        for (int jj = 0; jj < 4; ++jj)
          acc[i][jj] = f32x4{0.f, 0.f, 0.f, 0.f};
      // scr reads done before next epilogue (22 tile-barriers away); next
      // TILE touches Asd/Bsd (disjoint from scr) -> no extra barrier.
    }
  }

#undef LDAF
#undef LDBF
#undef TILE
}

extern "C" void kernel_launch(void* const* d_in, const int* in_sizes, int n_in,
                              void* d_out, int out_size, void* d_ws, size_t ws_size,
                              hipStream_t stream) {
  const float* X  = (const float*)d_in[0];
  const float* W1 = (const float*)d_in[1];
  const float* b1 = (const float*)d_in[2];
  const float* W2 = (const float*)d_in[3];
  const float* b2 = (const float*)d_in[4];

  // ws: Xb 46,137,344 | W1T 23,068,672  = 69,206,016 B (proven fits)
  u16* Xb  = (u16*)d_ws;
  u16* W1T = (u16*)((char*)d_ws + (size_t)BATCH * D_IN * 2);

  prep<<<CONV_BLOCKS + (D_IN / 64) * (D_HID / 64) * N_HEADS, 256, 0, stream>>>(
      (const float4*)X, (ushort4*)Xb, W1, W1T);

  mano_gemm<<<dim3(512), 256, 0, stream>>>(
      Xb, W1T, b1, W2, b2, (float*)d_out);
}